// Round 1
// baseline (277.771 us; speedup 1.0000x reference)
//
#include <hip/hip_runtime.h>
#include <math.h>

// MS-SSIM loss, 5 levels, 11x11 separable Gaussian window, zero padding.
// Inputs: pred, target float32 [16,3,512,512]. Output: scalar float32.
//
// Per level: fused separable conv of the 4 fields (a=p+t, b=p-t, a^2, b^2),
// per-pixel cs (or lum*cs at last level) accumulated into double accumulators
// in d_ws, plus fused 2x2 avg-pool producing the next level's inputs.

#define NIMG 48            // 16 * 3
#define OUTW 52            // output columns per wave strip (64 = 6 + 52 + 6)
#define TWO_C1 2.0e-4f     // 2 * (0.01*1.0)^2
#define TWO_C2 1.8e-3f     // 2 * (0.03*1.0)^2

struct GW { float g[11]; };

// One step of the sliding pipeline: load input row R (prefetched), stage
// (a,b,a2,b2) in the wave's LDS row window, horizontal 11-tap conv into
// ring slot SLOT, and (if DS) handle the fused 2x2 downsample for row R.
#define STEP_LOAD_H(R, SLOT)                                                   \
  do {                                                                         \
    const int r_ = (R);                                                        \
    const float p_ = pNxt, t_ = tNxt;                                          \
    {                                                                          \
      const int rn_ = r_ + 1;                                                  \
      pNxt = 0.f; tNxt = 0.f;                                                  \
      if ((unsigned)rn_ < (unsigned)H) {                                       \
        if (colv) {                                                            \
          const size_t ro_ = (size_t)rn_ * W + gx;                             \
          pNxt = Pi[ro_]; tNxt = Ti[ro_];                                      \
        }                                                                      \
      }                                                                        \
    }                                                                          \
    const float a_ = p_ + t_, b_ = p_ - t_;                                    \
    sWin[wid][6 + lane] = make_float4(a_, b_, a_ * a_, b_ * b_);               \
    asm volatile("s_waitcnt lgkmcnt(0)" ::: "memory");                         \
    float hA_ = 0.f, hB_ = 0.f, hA2_ = 0.f, hB2_ = 0.f;                        \
    _Pragma("unroll")                                                          \
    for (int k_ = 0; k_ < 11; ++k_) {                                          \
      const float4 v_ = sWin[wid][1 + lane + k_];                              \
      hA_  = __builtin_fmaf(g[k_], v_.x, hA_);                                 \
      hB_  = __builtin_fmaf(g[k_], v_.y, hB_);                                 \
      hA2_ = __builtin_fmaf(g[k_], v_.z, hA2_);                                \
      hB2_ = __builtin_fmaf(g[k_], v_.w, hB2_);                                \
    }                                                                          \
    bA[SLOT] = hA_; bB[SLOT] = hB_; bA2[SLOT] = hA2_; bB2[SLOT] = hB2_;        \
    if (DS && r_ >= y0 && r_ < y1) {                                           \
      if ((r_ & 1) == 0) { pr = p_; tr = t_; }                                 \
      else {                                                                   \
        float sp_ = pr + p_, st_ = tr + t_;                                    \
        sp_ += __shfl_xor(sp_, 1, 64);                                         \
        st_ += __shfl_xor(st_, 1, 64);                                         \
        if (outl && ((lane & 1) == 0)) {                                       \
          const size_t o_ = obase + (size_t)(r_ >> 1) * (W >> 1) + (gx >> 1);  \
          dsP[o_] = sp_ * 0.25f;                                               \
          dsT[o_] = st_ * 0.25f;                                               \
        }                                                                      \
      }                                                                        \
    }                                                                          \
  } while (0)

template <int DS, int LAST>
__global__ __launch_bounds__(256)
void msssim_level_k(const float* __restrict__ P, const float* __restrict__ T,
                    int H, int W, int strips, int chunks, int chunkH, int tasks,
                    float* __restrict__ dsP, float* __restrict__ dsT,
                    double* __restrict__ acc, GW gw) {
  // Per-wave LDS row window: 6 pad + 64 lanes + 6 pad entries of float4.
  __shared__ float4 sWin[4][76];
  __shared__ float sRed[4];

  const int tid = threadIdx.x;
  const int lane = tid & 63;
  const int wid = tid >> 6;
  const float* g = gw.g;

  float sum = 0.f;
  const int task = blockIdx.x * 4 + wid;

  if (task < tasks) {
    // task -> (img, chunk, strip)
    const int strip = task % strips;
    const int rem = task / strips;
    const int chunk = rem % chunks;
    const int img = rem / chunks;

    const int c0 = strip * OUTW - 6;       // even offset -> lane parity == gx parity
    const int gx = c0 + lane;
    const bool colv = (gx >= 0) && (gx < W);
    const bool outl = (lane >= 6) && (lane < 58) && (gx < W);
    const int y0 = chunk * chunkH;
    const int y1 = min(y0 + chunkH, H);
    const int nout = y1 - y0;

    const size_t ibase = (size_t)img * H * W;
    const float* Pi = P + ibase;
    const float* Ti = T + ibase;
    const size_t obase = DS ? ((size_t)img * (H >> 1) * (W >> 1)) : 0;

    // Zero this wave's pad slots (read only by invalid edge lanes).
    if (lane < 6) sWin[wid][lane] = make_float4(0.f, 0.f, 0.f, 0.f);
    else if (lane < 12) sWin[wid][lane + 64] = make_float4(0.f, 0.f, 0.f, 0.f);

    float bA[11], bB[11], bA2[11], bB2[11];
    float pr = 0.f, tr = 0.f;      // previous-row p,t for downsample
    float pNxt = 0.f, tNxt = 0.f;  // 1-row software prefetch

    // preload row y0-5
    {
      const int r0 = y0 - 5;
      if ((unsigned)r0 < (unsigned)H && colv) {
        const size_t ro = (size_t)r0 * W + gx;
        pNxt = Pi[ro]; tNxt = Ti[ro];
      }
    }

    // Prologue: fill ring slots 0..9 with rows y0-5 .. y0+4.
#pragma unroll
    for (int s = 0; s < 10; ++s) {
      STEP_LOAD_H(y0 - 5 + s, s);
    }

    // Main: output rows y0+i; new input row y0+5+i -> slot (i+10)%11.
    for (int base = 0; base < nout; base += 11) {
#pragma unroll
      for (int jj = 0; jj < 11; ++jj) {
        const int i = base + jj;
        if (i >= nout) break;  // wave-uniform
        STEP_LOAD_H(y0 + 5 + i, ((jj + 10) % 11));

        float A = 0.f, B = 0.f, EA2 = 0.f, EB2 = 0.f;
#pragma unroll
        for (int k = 0; k < 11; ++k) {
          const int s2 = (jj + k) % 11;
          A   = __builtin_fmaf(g[k], bA[s2], A);
          B   = __builtin_fmaf(g[k], bB[s2], B);
          EA2 = __builtin_fmaf(g[k], bA2[s2], EA2);
          EB2 = __builtin_fmaf(g[k], bB2[s2], EB2);
        }
        const float A2 = A * A, B2 = B * B;
        const float dAB = A2 - B2, sAB = A2 + B2;
        const float cn = (EA2 - EB2) - dAB + TWO_C2;
        const float cd = (EA2 + EB2) - sAB + TWO_C2;
        float val;
        if (LAST) {
          val = ((dAB + TWO_C1) * cn) / ((sAB + TWO_C1) * cd);
        } else {
          val = cn / cd;
        }
        if (outl) sum += val;
      }
    }
  }

  // Block reduction -> one double atomic per block.
#pragma unroll
  for (int off = 32; off > 0; off >>= 1) sum += __shfl_down(sum, off, 64);
  if (lane == 0) sRed[wid] = sum;
  __syncthreads();
  if (tid == 0) {
    const float s = sRed[0] + sRed[1] + sRed[2] + sRed[3];
    atomicAdd(acc, (double)s);
  }
}

__global__ void msssim_combine_k(const double* __restrict__ acc,
                                 float* __restrict__ out) {
  double ms = acc[4] / (48.0 * 32.0 * 32.0);                 // mean(lum*cs), level 4
  ms *= pow(acc[0] / (48.0 * 512.0 * 512.0), (double)0.0448f);
  ms *= pow(acc[1] / (48.0 * 256.0 * 256.0), (double)0.2856f);
  ms *= pow(acc[2] / (48.0 * 128.0 * 128.0), (double)0.3001f);
  ms *= pow(acc[3] / (48.0 * 64.0 * 64.0),  (double)0.2363f);
  out[0] = (float)(1.0 - ms);
}

extern "C" void kernel_launch(void* const* d_in, const int* in_sizes, int n_in,
                              void* d_out, int out_size, void* d_ws, size_t ws_size,
                              hipStream_t stream) {
  const float* pred = (const float*)d_in[0];
  const float* targ = (const float*)d_in[1];
  float* out = (float*)d_out;

  char* ws = (char*)d_ws;
  double* acc = (double*)ws;
  size_t off = 256;
  auto alloc = [&](size_t elems) {
    float* p = (float*)(ws + off);
    off += elems * sizeof(float);
    return p;
  };
  float* L1p = alloc((size_t)NIMG * 256 * 256);
  float* L1t = alloc((size_t)NIMG * 256 * 256);
  float* L2p = alloc((size_t)NIMG * 128 * 128);
  float* L2t = alloc((size_t)NIMG * 128 * 128);
  float* L3p = alloc((size_t)NIMG * 64 * 64);
  float* L3t = alloc((size_t)NIMG * 64 * 64);
  float* L4p = alloc((size_t)NIMG * 32 * 32);
  float* L4t = alloc((size_t)NIMG * 32 * 32);

  hipMemsetAsync(acc, 0, 5 * sizeof(double), stream);

  GW gw;
  {
    double gd[11], s = 0.0;
    for (int k = 0; k < 11; ++k) {
      const double c = (double)(k - 5);
      gd[k] = exp(-(c * c) / 4.5);  // 2*sigma^2 = 4.5
      s += gd[k];
    }
    for (int k = 0; k < 11; ++k) gw.g[k] = (float)(gd[k] / s);
  }

  auto launch = [&](const float* P, const float* T, int H, int W, int chunkH,
                    float* dP, float* dT, int accIdx, bool last) {
    const int strips = (W + OUTW - 1) / OUTW;
    const int chunks = (H + chunkH - 1) / chunkH;
    const int tasks = strips * chunks * NIMG;
    const int blocks = (tasks + 3) / 4;
    if (last) {
      msssim_level_k<0, 1><<<blocks, 256, 0, stream>>>(
          P, T, H, W, strips, chunks, chunkH, tasks, nullptr, nullptr,
          acc + accIdx, gw);
    } else {
      msssim_level_k<1, 0><<<blocks, 256, 0, stream>>>(
          P, T, H, W, strips, chunks, chunkH, tasks, dP, dT, acc + accIdx, gw);
    }
  };

  launch(pred, targ, 512, 512, 64, L1p, L1t, 0, false);
  launch(L1p, L1t, 256, 256, 32, L2p, L2t, 1, false);
  launch(L2p, L2t, 128, 128, 16, L3p, L3t, 2, false);
  launch(L3p, L3t, 64, 64, 16, L4p, L4t, 3, false);
  launch(L4p, L4t, 32, 32, 8, nullptr, nullptr, 4, true);

  msssim_combine_k<<<1, 1, 0, stream>>>(acc, out);
}